// Round 5
// baseline (2134.399 us; speedup 1.0000x reference)
//
#include <hip/hip_runtime.h>
#include <cstdint>
#include <cstddef>

typedef unsigned short u16;
typedef unsigned int u32;
typedef __attribute__((ext_vector_type(8))) short short8;
typedef __attribute__((ext_vector_type(4))) float f32x4;

#define S_LEN 2048
#define NBATCH 2
#define DM 1024
#define DK 32
#define NH 32
#define M_ROWS 4096
#define SCALE 0.17677669529663687f  // 1/sqrt(32)

// ---- fp32 -> bf16 hi/lo split (hi = truncation, lo = rne(x - hi)) ----------
__device__ __forceinline__ u16 bf16_rne(float f) {
  u32 u = __float_as_uint(f);
  u32 r = (u + 0x7FFFu + ((u >> 16) & 1u)) >> 16;
  return (u16)r;
}
__device__ __forceinline__ void split2(float x, u16& hi, u16& lo) {
  u32 u = __float_as_uint(x);
  hi = (u16)(u >> 16);
  float hif = __uint_as_float(u & 0xFFFF0000u);
  lo = bf16_rne(x - hif);
}

// ---------------------------------------------------------------------------
// split_x: fp32 array -> bf16 hi + lo arrays. 8 elems/thread, vectorized.
// (validated R4)
// ---------------------------------------------------------------------------
__global__ __launch_bounds__(256)
void split_x(const float* __restrict__ X, u16* __restrict__ Hi,
             u16* __restrict__ Lo) {
  const size_t i0 = ((size_t)blockIdx.x * 256 + threadIdx.x) * 8;
  const float4 v0 = *(const float4*)(X + i0);
  const float4 v1 = *(const float4*)(X + i0 + 4);
  const float f[8] = {v0.x, v0.y, v0.z, v0.w, v1.x, v1.y, v1.z, v1.w};
  u16 h[8], l[8];
#pragma unroll
  for (int e = 0; e < 8; ++e) split2(f[e], h[e], l[e]);
  uint4 hv, lv;
  hv.x = h[0] | ((u32)h[1] << 16); hv.y = h[2] | ((u32)h[3] << 16);
  hv.z = h[4] | ((u32)h[5] << 16); hv.w = h[6] | ((u32)h[7] << 16);
  lv.x = l[0] | ((u32)l[1] << 16); lv.y = l[2] | ((u32)l[3] << 16);
  lv.z = l[4] | ((u32)l[5] << 16); lv.w = l[6] | ((u32)l[7] << 16);
  *(uint4*)(Hi + i0) = hv;
  *(uint4*)(Lo + i0) = lv;
}

// ---------------------------------------------------------------------------
// tsplit: W (1024x1024 fp32) -> W^T hi/lo bf16 (N x K). (validated R4)
// ---------------------------------------------------------------------------
__global__ __launch_bounds__(256)
void tsplit(const float* __restrict__ W, u16* __restrict__ Thi,
            u16* __restrict__ Tlo) {
  __shared__ float tile[32][33];
  const int k0 = blockIdx.x * 32, n0 = blockIdx.y * 32;
  const int tx = threadIdx.x & 31, ty = threadIdx.x >> 5;  // ty 0..7
#pragma unroll
  for (int i = 0; i < 4; ++i)
    tile[ty + 8 * i][tx] = W[(size_t)(k0 + ty + 8 * i) * DM + n0 + tx];
  __syncthreads();
#pragma unroll
  for (int i = 0; i < 4; ++i) {
    const float v = tile[tx][ty + 8 * i];  // = W[k0+tx][n0+ty+8i]
    u16 h, l;
    split2(v, h, l);
    const size_t d = (size_t)(n0 + ty + 8 * i) * DM + k0 + tx;
    Thi[d] = h;
    Tlo[d] = l;
  }
}

// ---------------------------------------------------------------------------
// bf16x3 MFMA GEMM (validated R4): C(4096x1024) = A @ B^T + bias, fp32 out.
// ---------------------------------------------------------------------------
__global__ __launch_bounds__(256)
void gemm_mfma(const u16* __restrict__ Ahi, const u16* __restrict__ Alo,
               const u16* __restrict__ Bhi, const u16* __restrict__ Blo,
               const float* __restrict__ bias, float* __restrict__ C) {
  __shared__ u16 lds[4][8][64][8];  // 32 KB: Ahi, Alo, Bhi, Blo tiles
  const int t = threadIdx.x;
  const int bid = blockIdx.x;
  const int swz = (bid & 7) * 32 + (bid >> 3);  // 256 % 8 == 0: bijective
  const int m0 = (swz & 31) * 128;
  const int n0 = (swz >> 5) * 128;

  const int r = t >> 1, h = t & 1;
  const size_t arow = (size_t)(m0 + r) * DM;
  const size_t brow = (size_t)(n0 + r) * DM;
  const int koff = 16 * h;
  const int mt = r >> 4;
  const int l0w = 32 * h + (r & 15);

  const int wr = t >> 7, wc = (t >> 6) & 1, l = t & 63;

  f32x4 acc[4][4];
#pragma unroll
  for (int i = 0; i < 4; ++i)
#pragma unroll
    for (int j = 0; j < 4; ++j) acc[i][j] = (f32x4){0.f, 0.f, 0.f, 0.f};

  int4 rah0, rah1, ral0, ral1, rbh0, rbh1, rbl0, rbl1;
#define GLOAD(k0)                                        \
  do {                                                   \
    const u16* pa = Ahi + arow + (k0) + koff;            \
    rah0 = *(const int4*)pa;                             \
    rah1 = *(const int4*)(pa + 8);                       \
    const u16* pal = Alo + arow + (k0) + koff;           \
    ral0 = *(const int4*)pal;                            \
    ral1 = *(const int4*)(pal + 8);                      \
    const u16* pb = Bhi + brow + (k0) + koff;            \
    rbh0 = *(const int4*)pb;                             \
    rbh1 = *(const int4*)(pb + 8);                       \
    const u16* pbl = Blo + brow + (k0) + koff;           \
    rbl0 = *(const int4*)pbl;                            \
    rbl1 = *(const int4*)(pbl + 8);                      \
  } while (0)

  GLOAD(0);

  for (int ks = 0; ks < 32; ++ks) {
    *(int4*)&lds[0][mt][l0w][0] = rah0;
    *(int4*)&lds[0][mt][l0w + 16][0] = rah1;
    *(int4*)&lds[1][mt][l0w][0] = ral0;
    *(int4*)&lds[1][mt][l0w + 16][0] = ral1;
    *(int4*)&lds[2][mt][l0w][0] = rbh0;
    *(int4*)&lds[2][mt][l0w + 16][0] = rbh1;
    *(int4*)&lds[3][mt][l0w][0] = rbl0;
    *(int4*)&lds[3][mt][l0w + 16][0] = rbl1;
    __syncthreads();
    if (ks < 31) GLOAD((ks + 1) * 32);  // in flight under MFMA below

    short8 ah[4], al[4], bh[4], bl[4];
#pragma unroll
    for (int i = 0; i < 4; ++i) {
      ah[i] = *(const short8*)&lds[0][wr * 4 + i][l][0];
      al[i] = *(const short8*)&lds[1][wr * 4 + i][l][0];
      bh[i] = *(const short8*)&lds[2][wc * 4 + i][l][0];
      bl[i] = *(const short8*)&lds[3][wc * 4 + i][l][0];
    }
#pragma unroll
    for (int i = 0; i < 4; ++i)
#pragma unroll
      for (int j = 0; j < 4; ++j) {
        acc[i][j] = __builtin_amdgcn_mfma_f32_16x16x32_bf16(ah[i], bh[j],
                                                            acc[i][j], 0, 0, 0);
        acc[i][j] = __builtin_amdgcn_mfma_f32_16x16x32_bf16(ah[i], bl[j],
                                                            acc[i][j], 0, 0, 0);
        acc[i][j] = __builtin_amdgcn_mfma_f32_16x16x32_bf16(al[i], bh[j],
                                                            acc[i][j], 0, 0, 0);
      }
    __syncthreads();
  }
#undef GLOAD

  const int lcol = l & 15;
  float bj[4];
#pragma unroll
  for (int j = 0; j < 4; ++j) bj[j] = bias[n0 + wc * 64 + j * 16 + lcol];
#pragma unroll
  for (int i = 0; i < 4; ++i) {
    const int row0 = m0 + wr * 64 + i * 16 + (l >> 4) * 4;
#pragma unroll
    for (int j = 0; j < 4; ++j) {
      float* cp = C + (size_t)row0 * DM + n0 + wc * 64 + j * 16 + lcol;
#pragma unroll
      for (int q = 0; q < 4; ++q) cp[(size_t)q * DM] = acc[i][j][q] + bj[j];
    }
  }
}

// ---------------------------------------------------------------------------
// K/V projection (unchanged, validated R2).
// ---------------------------------------------------------------------------
__global__ __launch_bounds__(256)
void kv_proj(const float* __restrict__ X, const float* __restrict__ Wk,
             const float* __restrict__ bk, const float* __restrict__ Wv,
             const float* __restrict__ bv, float* __restrict__ Kp,
             float* __restrict__ Vp) {
  const int col = threadIdx.x & 63;
  const int r = threadIdx.x >> 6;
  const int row = blockIdx.x * 4 + r;
  const float* __restrict__ xr = X + (size_t)row * DM;
  const bool isK = col < DK;
  const int cc = isK ? col : col - DK;
  const float* __restrict__ w = (isK ? Wk : Wv) + cc;
  float acc = isK ? bk[cc] : bv[cc];
#pragma unroll 8
  for (int k = 0; k < DM; ++k) acc = fmaf(xr[k], w[(size_t)k * DK], acc);
  (isK ? Kp : Vp)[(size_t)row * DK + cc] = acc;
}

// ---------------------------------------------------------------------------
// Flash v3: occupancy fix. R4 counters showed flash2 latency-bound at 23%
// occupancy (grid-limited), VALUBusy 25%: compiler scalarized the uniform
// K/V loads (SGPR=112) and serialized on lgkmcnt. Fix: 1024-thread blocks,
// 4-way t-split within the block (chunk c covers t in [c*512,(c+1)*512)),
// partial (acc, lsum) merged via LDS (valid because w=exp(s) has no running
// max: partials just add). 512 blocks x 16 waves = 8192 waves -> ~100%
// occupancy; VALU issue port becomes the limit (~235 us floor).
// Grid: (S/256, NH, NBATCH) = (8,32,2), 1024 threads.
// ---------------------------------------------------------------------------
__global__ __launch_bounds__(1024, 4)
void flash3(const float* __restrict__ Q, const float* __restrict__ Kp,
            const float* __restrict__ Vp, u16* __restrict__ Ohi,
            u16* __restrict__ Olo) {
  __shared__ float red[256][33];  // stride 33 words -> conflict-free columns
  const int a = blockIdx.y;
  const int b = blockIdx.z;
  const int tid = threadIdx.x;
  const int r = tid & 255;
  const int c = tid >> 8;  // chunk 0..3, wave-uniform
  const int row = blockIdx.x * 256 + r;
  const int t0 = c * 512;

  const float* __restrict__ qp = Q + (size_t)(b * S_LEN + row) * DM + a * DK;
  float4 q[8], acc[8];
#pragma unroll
  for (int j = 0; j < 8; ++j) {
    float4 t = *(const float4*)(qp + 4 * j);
    t.x *= SCALE; t.y *= SCALE; t.z *= SCALE; t.w *= SCALE;
    q[j] = t;
    acc[j] = make_float4(0.f, 0.f, 0.f, 0.f);
  }
  float lsum = 0.f;

  const float4* __restrict__ Kb = (const float4*)(Kp + (size_t)b * S_LEN * DK);
  const float4* __restrict__ Vb = (const float4*)(Vp + (size_t)b * S_LEN * DK);

  float4 k0[8], v0[8], k1[8], v1[8];
#pragma unroll
  for (int j = 0; j < 8; ++j) {
    k0[j] = Kb[(size_t)t0 * 8 + j];
    v0[j] = Vb[(size_t)t0 * 8 + j];
  }

  for (int t = t0; t < t0 + 512; t += 2) {
    {
      const float4* __restrict__ kp = Kb + (size_t)(t + 1) * 8;
      const float4* __restrict__ vp = Vb + (size_t)(t + 1) * 8;
#pragma unroll
      for (int j = 0; j < 8; ++j) { k1[j] = kp[j]; v1[j] = vp[j]; }
    }
    {
      float4 s4 = make_float4(0.f, 0.f, 0.f, 0.f);
#pragma unroll
      for (int j = 0; j < 8; ++j) {
        s4.x = fmaf(q[j].x, k0[j].x, s4.x);
        s4.y = fmaf(q[j].y, k0[j].y, s4.y);
        s4.z = fmaf(q[j].z, k0[j].z, s4.z);
        s4.w = fmaf(q[j].w, k0[j].w, s4.w);
      }
      const float w = __expf((s4.x + s4.y) + (s4.z + s4.w));
      lsum += w;
#pragma unroll
      for (int j = 0; j < 8; ++j) {
        acc[j].x = fmaf(w, v0[j].x, acc[j].x);
        acc[j].y = fmaf(w, v0[j].y, acc[j].y);
        acc[j].z = fmaf(w, v0[j].z, acc[j].z);
        acc[j].w = fmaf(w, v0[j].w, acc[j].w);
      }
    }
    {  // t+2 hits next chunk's rows or (c==3 tail) the slack region: in-bounds
      const float4* __restrict__ kp = Kb + (size_t)(t + 2) * 8;
      const float4* __restrict__ vp = Vb + (size_t)(t + 2) * 8;
#pragma unroll
      for (int j = 0; j < 8; ++j) { k0[j] = kp[j]; v0[j] = vp[j]; }
    }
    {
      float4 s4 = make_float4(0.f, 0.f, 0.f, 0.f);
#pragma unroll
      for (int j = 0; j < 8; ++j) {
        s4.x = fmaf(q[j].x, k1[j].x, s4.x);
        s4.y = fmaf(q[j].y, k1[j].y, s4.y);
        s4.z = fmaf(q[j].z, k1[j].z, s4.z);
        s4.w = fmaf(q[j].w, k1[j].w, s4.w);
      }
      const float w = __expf((s4.x + s4.y) + (s4.z + s4.w));
      lsum += w;
#pragma unroll
      for (int j = 0; j < 8; ++j) {
        acc[j].x = fmaf(w, v1[j].x, acc[j].x);
        acc[j].y = fmaf(w, v1[j].y, acc[j].y);
        acc[j].z = fmaf(w, v1[j].z, acc[j].z);
        acc[j].w = fmaf(w, v1[j].w, acc[j].w);
      }
    }
  }

  // merge chunk partials into chunk 0 (3 rounds through LDS)
#pragma unroll
  for (int src = 1; src < 4; ++src) {
    if (c == src) {
#pragma unroll
      for (int j = 0; j < 8; ++j) {
        red[r][4 * j + 0] = acc[j].x;
        red[r][4 * j + 1] = acc[j].y;
        red[r][4 * j + 2] = acc[j].z;
        red[r][4 * j + 3] = acc[j].w;
      }
      red[r][32] = lsum;
    }
    __syncthreads();
    if (c == 0) {
#pragma unroll
      for (int j = 0; j < 8; ++j) {
        acc[j].x += red[r][4 * j + 0];
        acc[j].y += red[r][4 * j + 1];
        acc[j].z += red[r][4 * j + 2];
        acc[j].w += red[r][4 * j + 3];
      }
      lsum += red[r][32];
    }
    __syncthreads();
  }

  if (c == 0) {
    const float inv = 1.f / lsum;
    const size_t off = (size_t)(b * S_LEN + row) * DM + a * DK;
    u16* __restrict__ oh = Ohi + off;
    u16* __restrict__ ol = Olo + off;
#pragma unroll
    for (int j = 0; j < 8; ++j) {
      const float u0 = acc[j].x * inv, u1 = acc[j].y * inv;
      const float u2 = acc[j].z * inv, u3 = acc[j].w * inv;
      u16 h0, h1, h2, h3, e0, e1, e2, e3;
      split2(u0, h0, e0); split2(u1, h1, e1);
      split2(u2, h2, e2); split2(u3, h3, e3);
      uint2 hv, lv;
      hv.x = h0 | ((u32)h1 << 16); hv.y = h2 | ((u32)h3 << 16);
      lv.x = e0 | ((u32)e1 << 16); lv.y = e2 | ((u32)e3 << 16);
      *(uint2*)(oh + 4 * j) = hv;
      *(uint2*)(ol + 4 * j) = lv;
    }
  }
}

// ---------------------------------------------------------------------------
// Workspace layout (25.5 MB), unchanged from validated R4:
//   [0,8M) Xhi (aliases attn_hi)   [8M,16M) Xlo (aliases attn_lo)
//   [16M,+768K) Kp (512K+slack)    [+768K,+1.5M) Vp (512K+slack)
//   [17.5M..25.5M) Wqt_hi, Wqt_lo, Wot_hi, Wot_lo (2MB each)
// d_out doubles as Q scratch.
// ---------------------------------------------------------------------------
extern "C" void kernel_launch(void* const* d_in, const int* in_sizes, int n_in,
                              void* d_out, int out_size, void* d_ws,
                              size_t ws_size, hipStream_t stream) {
  const float* x  = (const float*)d_in[0];
  const float* Wq = (const float*)d_in[1];
  const float* bq = (const float*)d_in[2];
  const float* Wk = (const float*)d_in[3];
  const float* bk = (const float*)d_in[4];
  const float* Wv = (const float*)d_in[5];
  const float* bv = (const float*)d_in[6];
  const float* Wo = (const float*)d_in[7];
  const float* bo = (const float*)d_in[8];
  float* out = (float*)d_out;

  char* ws = (char*)d_ws;
  const size_t MB = 1024 * 1024;
  u16* Xhi = (u16*)ws;                       // + attn_hi alias
  u16* Xlo = (u16*)(ws + 8 * MB);            // + attn_lo alias
  float* Kp = (float*)(ws + 16 * MB);
  float* Vp = (float*)(ws + 16 * MB + 768 * 1024);
  u16* Wqthi = (u16*)(ws + 17 * MB + 512 * 1024);
  u16* Wqtlo = (u16*)(ws + 19 * MB + 512 * 1024);
  u16* Wothi = (u16*)(ws + 21 * MB + 512 * 1024);
  u16* Wotlo = (u16*)(ws + 23 * MB + 512 * 1024);
  float* Qbuf = out;

  hipLaunchKernelGGL(split_x, dim3(2048), dim3(256), 0, stream, x, Xhi, Xlo);
  hipLaunchKernelGGL(tsplit, dim3(32, 32), dim3(256), 0, stream, Wq, Wqthi,
                     Wqtlo);
  hipLaunchKernelGGL(tsplit, dim3(32, 32), dim3(256), 0, stream, Wo, Wothi,
                     Wotlo);
  hipLaunchKernelGGL(kv_proj, dim3(M_ROWS / 4), dim3(256), 0, stream, x, Wk,
                     bk, Wv, bv, Kp, Vp);
  hipLaunchKernelGGL(gemm_mfma, dim3(256), dim3(256), 0, stream, Xhi, Xlo,
                     Wqthi, Wqtlo, bq, Qbuf);
  hipLaunchKernelGGL(flash3, dim3(S_LEN / 256, NH, NBATCH), dim3(1024), 0,
                     stream, Qbuf, Kp, Vp, Xhi, Xlo);
  hipLaunchKernelGGL(gemm_mfma, dim3(256), dim3(256), 0, stream, Xhi, Xlo,
                     Wothi, Wotlo, bo, out);
}

// Round 6
// 350.353 us; speedup vs baseline: 6.0921x; 6.0921x over previous
//
#include <hip/hip_runtime.h>
#include <cstdint>
#include <cstddef>

typedef unsigned short u16;
typedef unsigned int u32;
typedef __attribute__((ext_vector_type(8))) short short8;
typedef __attribute__((ext_vector_type(4))) float f32x4;

#define S_LEN 2048
#define NBATCH 2
#define DM 1024
#define DK 32
#define NH 32
#define M_ROWS 4096
#define SCALE 0.17677669529663687f  // 1/sqrt(32)

// ---- fp32 -> bf16 hi/lo split (hi = truncation, lo = rne(x - hi)) ----------
__device__ __forceinline__ u16 bf16_rne(float f) {
  u32 u = __float_as_uint(f);
  u32 r = (u + 0x7FFFu + ((u >> 16) & 1u)) >> 16;
  return (u16)r;
}
__device__ __forceinline__ void split2(float x, u16& hi, u16& lo) {
  u32 u = __float_as_uint(x);
  hi = (u16)(u >> 16);
  float hif = __uint_as_float(u & 0xFFFF0000u);
  lo = bf16_rne(x - hif);
}
__device__ __forceinline__ u32 pack2(float lo, float hi) {
  return (u32)bf16_rne(lo) | ((u32)bf16_rne(hi) << 16);
}

// ---------------------------------------------------------------------------
// split_x: fp32 array -> bf16 hi + lo arrays. (validated R4)
// ---------------------------------------------------------------------------
__global__ __launch_bounds__(256)
void split_x(const float* __restrict__ X, u16* __restrict__ Hi,
             u16* __restrict__ Lo) {
  const size_t i0 = ((size_t)blockIdx.x * 256 + threadIdx.x) * 8;
  const float4 v0 = *(const float4*)(X + i0);
  const float4 v1 = *(const float4*)(X + i0 + 4);
  const float f[8] = {v0.x, v0.y, v0.z, v0.w, v1.x, v1.y, v1.z, v1.w};
  u16 h[8], l[8];
#pragma unroll
  for (int e = 0; e < 8; ++e) split2(f[e], h[e], l[e]);
  uint4 hv, lv;
  hv.x = h[0] | ((u32)h[1] << 16); hv.y = h[2] | ((u32)h[3] << 16);
  hv.z = h[4] | ((u32)h[5] << 16); hv.w = h[6] | ((u32)h[7] << 16);
  lv.x = l[0] | ((u32)l[1] << 16); lv.y = l[2] | ((u32)l[3] << 16);
  lv.z = l[4] | ((u32)l[5] << 16); lv.w = l[6] | ((u32)l[7] << 16);
  *(uint4*)(Hi + i0) = hv;
  *(uint4*)(Lo + i0) = lv;
}

// ---------------------------------------------------------------------------
// tsplit: W (1024x1024 fp32) -> W^T hi/lo bf16 (N x K). (validated R4)
// ---------------------------------------------------------------------------
__global__ __launch_bounds__(256)
void tsplit(const float* __restrict__ W, u16* __restrict__ Thi,
            u16* __restrict__ Tlo) {
  __shared__ float tile[32][33];
  const int k0 = blockIdx.x * 32, n0 = blockIdx.y * 32;
  const int tx = threadIdx.x & 31, ty = threadIdx.x >> 5;
#pragma unroll
  for (int i = 0; i < 4; ++i)
    tile[ty + 8 * i][tx] = W[(size_t)(k0 + ty + 8 * i) * DM + n0 + tx];
  __syncthreads();
#pragma unroll
  for (int i = 0; i < 4; ++i) {
    const float v = tile[tx][ty + 8 * i];
    u16 h, l;
    split2(v, h, l);
    const size_t d = (size_t)(n0 + ty + 8 * i) * DM + k0 + tx;
    Thi[d] = h;
    Tlo[d] = l;
  }
}

// ---------------------------------------------------------------------------
// bf16x3 MFMA GEMM (validated R4), now templated epilogue:
//  QMODE=0: C = A@B^T + bias (fp32 out)
//  QMODE=1: Q = (A@B^T + bias)*SCALE, written as bf16 hi/lo (Ohi/Olo)
// ---------------------------------------------------------------------------
template <int QMODE>
__global__ __launch_bounds__(256)
void gemm_mfma(const u16* __restrict__ Ahi, const u16* __restrict__ Alo,
               const u16* __restrict__ Bhi, const u16* __restrict__ Blo,
               const float* __restrict__ bias, float* __restrict__ C,
               u16* __restrict__ Ohi, u16* __restrict__ Olo) {
  __shared__ u16 lds[4][8][64][8];
  const int t = threadIdx.x;
  const int bid = blockIdx.x;
  const int swz = (bid & 7) * 32 + (bid >> 3);
  const int m0 = (swz & 31) * 128;
  const int n0 = (swz >> 5) * 128;

  const int r = t >> 1, h = t & 1;
  const size_t arow = (size_t)(m0 + r) * DM;
  const size_t brow = (size_t)(n0 + r) * DM;
  const int koff = 16 * h;
  const int mt = r >> 4;
  const int l0w = 32 * h + (r & 15);

  const int wr = t >> 7, wc = (t >> 6) & 1, l = t & 63;

  f32x4 acc[4][4];
#pragma unroll
  for (int i = 0; i < 4; ++i)
#pragma unroll
    for (int j = 0; j < 4; ++j) acc[i][j] = (f32x4){0.f, 0.f, 0.f, 0.f};

  int4 rah0, rah1, ral0, ral1, rbh0, rbh1, rbl0, rbl1;
#define GLOAD(k0)                                        \
  do {                                                   \
    const u16* pa = Ahi + arow + (k0) + koff;            \
    rah0 = *(const int4*)pa;                             \
    rah1 = *(const int4*)(pa + 8);                       \
    const u16* pal = Alo + arow + (k0) + koff;           \
    ral0 = *(const int4*)pal;                            \
    ral1 = *(const int4*)(pal + 8);                      \
    const u16* pb = Bhi + brow + (k0) + koff;            \
    rbh0 = *(const int4*)pb;                             \
    rbh1 = *(const int4*)(pb + 8);                       \
    const u16* pbl = Blo + brow + (k0) + koff;           \
    rbl0 = *(const int4*)pbl;                            \
    rbl1 = *(const int4*)(pbl + 8);                      \
  } while (0)

  GLOAD(0);

  for (int ks = 0; ks < 32; ++ks) {
    *(int4*)&lds[0][mt][l0w][0] = rah0;
    *(int4*)&lds[0][mt][l0w + 16][0] = rah1;
    *(int4*)&lds[1][mt][l0w][0] = ral0;
    *(int4*)&lds[1][mt][l0w + 16][0] = ral1;
    *(int4*)&lds[2][mt][l0w][0] = rbh0;
    *(int4*)&lds[2][mt][l0w + 16][0] = rbh1;
    *(int4*)&lds[3][mt][l0w][0] = rbl0;
    *(int4*)&lds[3][mt][l0w + 16][0] = rbl1;
    __syncthreads();
    if (ks < 31) GLOAD((ks + 1) * 32);

    short8 ah[4], al[4], bh[4], bl[4];
#pragma unroll
    for (int i = 0; i < 4; ++i) {
      ah[i] = *(const short8*)&lds[0][wr * 4 + i][l][0];
      al[i] = *(const short8*)&lds[1][wr * 4 + i][l][0];
      bh[i] = *(const short8*)&lds[2][wc * 4 + i][l][0];
      bl[i] = *(const short8*)&lds[3][wc * 4 + i][l][0];
    }
#pragma unroll
    for (int i = 0; i < 4; ++i)
#pragma unroll
      for (int j = 0; j < 4; ++j) {
        acc[i][j] = __builtin_amdgcn_mfma_f32_16x16x32_bf16(ah[i], bh[j],
                                                            acc[i][j], 0, 0, 0);
        acc[i][j] = __builtin_amdgcn_mfma_f32_16x16x32_bf16(ah[i], bl[j],
                                                            acc[i][j], 0, 0, 0);
        acc[i][j] = __builtin_amdgcn_mfma_f32_16x16x32_bf16(al[i], bh[j],
                                                            acc[i][j], 0, 0, 0);
      }
    __syncthreads();
  }
#undef GLOAD

  const int lcol = l & 15;
  float bj[4];
#pragma unroll
  for (int j = 0; j < 4; ++j) bj[j] = bias[n0 + wc * 64 + j * 16 + lcol];
#pragma unroll
  for (int i = 0; i < 4; ++i) {
    const int row0 = m0 + wr * 64 + i * 16 + (l >> 4) * 4;
#pragma unroll
    for (int j = 0; j < 4; ++j) {
      const int coln = n0 + wc * 64 + j * 16 + lcol;
#pragma unroll
      for (int q = 0; q < 4; ++q) {
        const float val = acc[i][j][q] + bj[j];
        if constexpr (QMODE == 0) {
          C[(size_t)(row0 + q) * DM + coln] = val;
        } else {
          u16 hh, ll;
          split2(val * SCALE, hh, ll);
          Ohi[(size_t)(row0 + q) * DM + coln] = hh;
          Olo[(size_t)(row0 + q) * DM + coln] = ll;
        }
      }
    }
  }
}

// ---------------------------------------------------------------------------
// K/V projection -> bf16 hi/lo. K row-major [row][k] (frag-ready for QK^T);
// V transposed [b][e][t] (frag-ready as PV's B operand). fp32 accumulate.
// ---------------------------------------------------------------------------
__global__ __launch_bounds__(256)
void kv_proj(const float* __restrict__ X, const float* __restrict__ Wk,
             const float* __restrict__ bk, const float* __restrict__ Wv,
             const float* __restrict__ bv, u16* __restrict__ Khi,
             u16* __restrict__ Klo, u16* __restrict__ Vthi,
             u16* __restrict__ Vtlo) {
  const int col = threadIdx.x & 63;
  const int rr = threadIdx.x >> 6;
  const int row = blockIdx.x * 4 + rr;
  const float* __restrict__ xr = X + (size_t)row * DM;
  const bool isK = col < DK;
  const int cc = isK ? col : col - DK;
  const float* __restrict__ w = (isK ? Wk : Wv) + cc;
  float acc = isK ? bk[cc] : bv[cc];
#pragma unroll 8
  for (int k = 0; k < DM; ++k) acc = fmaf(xr[k], w[(size_t)k * DK], acc);
  u16 h, l;
  split2(acc, h, l);
  if (isK) {
    Khi[(size_t)row * DK + cc] = h;
    Klo[(size_t)row * DK + cc] = l;
  } else {
    const size_t d =
        (size_t)(row >> 11) * DK * S_LEN + (size_t)cc * S_LEN + (row & 2047);
    Vthi[d] = h;
    Vtlo[d] = l;
  }
}

// ---------------------------------------------------------------------------
// MFMA flash attention. Per (b,a): S^T-tile = mfma(K_frag, Q_frag) so lane
// holds P[t...][q=l&15]; exp (no max -- scores bounded, validated R2/R4);
// P->bf16, wave-private LDS relayout to PV A-frag; O += mfma(P, Vh) +
// mfma(P, Vl). lsum in fp32, normalize at end (shfl_xor + bpermute).
// Block: 256 thr = 4 waves, each wave 32 q-rows (2 m-tiles); K/V t32-tile
// staged to frag-major LDS per iter (gemm_mfma's validated 2-barrier loop).
// Grid (16, 32, 2) = 1024 blocks = exactly 4 resident blocks/CU.
// ---------------------------------------------------------------------------
__global__ __launch_bounds__(256, 4)
void flash_mfma(const u16* __restrict__ Qhi, const u16* __restrict__ Qlo,
                const u16* __restrict__ Khi, const u16* __restrict__ Klo,
                const u16* __restrict__ Vthi, const u16* __restrict__ Vtlo,
                u16* __restrict__ Ohi, u16* __restrict__ Olo) {
  __shared__ u16 stg[4][2][64][8];   // [Kh,Kl,Vh,Vl][16-tile][lane][8] 8KB
  __shared__ u16 plds[4][2][64][8];  // [wave][mt][lane][8]             8KB
  const int a = blockIdx.y, b = blockIdx.z;
  const int tid = threadIdx.x;
  const int wv = tid >> 6, l = tid & 63;
  const int lq = l & 15, lc = l >> 4;
  const int q0w = blockIdx.x * 128 + wv * 32;

  // Q fragments (SCALE pre-folded at Q-proj epilogue)
  short8 qh[2], ql[2];
#pragma unroll
  for (int mt = 0; mt < 2; ++mt) {
    const size_t off =
        (size_t)(b * S_LEN + q0w + mt * 16 + lq) * DM + a * DK + lc * 8;
    qh[mt] = *(const short8*)(Qhi + off);
    ql[mt] = *(const short8*)(Qlo + off);
  }

  f32x4 oacc[2][2];
#pragma unroll
  for (int mt = 0; mt < 2; ++mt)
#pragma unroll
    for (int et = 0; et < 2; ++et) oacc[mt][et] = (f32x4){0.f, 0.f, 0.f, 0.f};
  float lsum[2] = {0.f, 0.f};

  // staging: thread -> one K 16B-chunk + one V 16B-chunk (frag-major dest)
  const int g = tid & 127, sr = g >> 2, sc = g & 3;
  const u16* __restrict__ srcK =
      (tid < 128 ? Khi : Klo) + (size_t)(b * S_LEN + sr) * DK + sc * 8;
  const u16* __restrict__ srcV = (tid < 128 ? Vthi : Vtlo) +
                                 (size_t)b * DK * S_LEN + (size_t)sr * S_LEN +
                                 sc * 8;
  u16* const dstK = &stg[tid >> 7][sr >> 4][(sc << 4) | (sr & 15)][0];
  u16* const dstV = &stg[2 + (tid >> 7)][sr >> 4][(sc << 4) | (sr & 15)][0];

  int4 regK = *(const int4*)srcK;
  int4 regV = *(const int4*)srcV;

  for (int it = 0; it < 64; ++it) {
    *(int4*)dstK = regK;
    *(int4*)dstV = regV;
    __syncthreads();  // stage visible
    if (it < 63) {
      const int t0n = (it + 1) * 32;
      regK = *(const int4*)(srcK + (size_t)t0n * DK);
      regV = *(const int4*)(srcV + t0n);
    }
    short8 kh[2], kl[2], vh[2], vl[2];
#pragma unroll
    for (int tt = 0; tt < 2; ++tt) {
      kh[tt] = *(const short8*)&stg[0][tt][l][0];
      kl[tt] = *(const short8*)&stg[1][tt][l][0];
      vh[tt] = *(const short8*)&stg[2][tt][l][0];
      vl[tt] = *(const short8*)&stg[3][tt][l][0];
    }
#pragma unroll
    for (int mt = 0; mt < 2; ++mt) {
      f32x4 s0 = (f32x4){0.f, 0.f, 0.f, 0.f};
      f32x4 s1 = (f32x4){0.f, 0.f, 0.f, 0.f};
      // bf16x3 scores (S^T: rows t, cols q)
      s0 = __builtin_amdgcn_mfma_f32_16x16x32_bf16(kh[0], qh[mt], s0, 0, 0, 0);
      s0 = __builtin_amdgcn_mfma_f32_16x16x32_bf16(kh[0], ql[mt], s0, 0, 0, 0);
      s0 = __builtin_amdgcn_mfma_f32_16x16x32_bf16(kl[0], qh[mt], s0, 0, 0, 0);
      s1 = __builtin_amdgcn_mfma_f32_16x16x32_bf16(kh[1], qh[mt], s1, 0, 0, 0);
      s1 = __builtin_amdgcn_mfma_f32_16x16x32_bf16(kh[1], ql[mt], s1, 0, 0, 0);
      s1 = __builtin_amdgcn_mfma_f32_16x16x32_bf16(kl[1], qh[mt], s1, 0, 0, 0);
      const float e0 = __expf(s0[0]), e1 = __expf(s0[1]);
      const float e2 = __expf(s0[2]), e3 = __expf(s0[3]);
      const float e4 = __expf(s1[0]), e5 = __expf(s1[1]);
      const float e6 = __expf(s1[2]), e7 = __expf(s1[3]);
      lsum[mt] += ((e0 + e1) + (e2 + e3)) + ((e4 + e5) + (e6 + e7));
      // lane holds P[t = lc*4 + j][q = lq] (tile0) and t+16 (tile1);
      // scatter into PV A-frag layout: row q, t-chunk contiguous 8
      const u32 pA = pack2(e0, e1), pB = pack2(e2, e3);
      const u32 pC = pack2(e4, e5), pD = pack2(e6, e7);
      const int fl1 = ((lc >> 1) << 4) | lq;        // t-chunk (lc*4)>>3
      const int fl2 = (((lc >> 1) + 2) << 4) | lq;  // tile1: t+16
      *(uint2*)&plds[wv][mt][fl1][(lc & 1) * 4] = make_uint2(pA, pB);
      *(uint2*)&plds[wv][mt][fl2][(lc & 1) * 4] = make_uint2(pC, pD);
    }
    __syncthreads();  // P visible + stage fully consumed
#pragma unroll
    for (int mt = 0; mt < 2; ++mt) {
      const short8 pf = *(const short8*)&plds[wv][mt][l][0];
      oacc[mt][0] = __builtin_amdgcn_mfma_f32_16x16x32_bf16(pf, vh[0],
                                                            oacc[mt][0], 0, 0, 0);
      oacc[mt][0] = __builtin_amdgcn_mfma_f32_16x16x32_bf16(pf, vl[0],
                                                            oacc[mt][0], 0, 0, 0);
      oacc[mt][1] = __builtin_amdgcn_mfma_f32_16x16x32_bf16(pf, vh[1],
                                                            oacc[mt][1], 0, 0, 0);
      oacc[mt][1] = __builtin_amdgcn_mfma_f32_16x16x32_bf16(pf, vl[1],
                                                            oacc[mt][1], 0, 0, 0);
    }
  }

  // epilogue: row sums -> 1/lsum -> normalize -> bf16 hi/lo out
#pragma unroll
  for (int mt = 0; mt < 2; ++mt) {
    float s = lsum[mt];
    s += __shfl_xor(s, 16);
    s += __shfl_xor(s, 32);               // all lanes: row-sum for row lq
    const float inv = 1.f / s;
    float invr[4];
#pragma unroll
    for (int rg = 0; rg < 4; ++rg)        // inv for row lc*4+rg
      invr[rg] = __int_as_float(__builtin_amdgcn_ds_bpermute(
          (((lc << 2) | rg)) << 2, __float_as_int(inv)));
    const size_t rb = (size_t)(b * S_LEN + q0w + mt * 16 + lc * 4);
#pragma unroll
    for (int et = 0; et < 2; ++et) {
#pragma unroll
      for (int rg = 0; rg < 4; ++rg) {
        const float val = oacc[mt][et][rg] * invr[rg];
        u16 hh, ll;
        split2(val, hh, ll);
        const size_t idx = (rb + rg) * DM + a * DK + et * 16 + lq;
        Ohi[idx] = hh;
        Olo[idx] = ll;
      }
    }
  }
}

// ---------------------------------------------------------------------------
// Workspace (25 MB):
//  [0,8M)   Xhi / attnHi alias      [8M,16M)  Xlo / attnLo alias
//  [16M,+256K) Khi  (+256K) Klo  (+256K) Vthi  (+256K) Vtlo   -> ends 17M
//  [17M) Wqthi 2M  [19M) Wqtlo  [21M) Wothi  [23M) Wotlo      -> ends 25M
// d_out (16MB) holds Qhi (8MB) + Qlo (8MB) until O-proj overwrites it.
// ---------------------------------------------------------------------------
extern "C" void kernel_launch(void* const* d_in, const int* in_sizes, int n_in,
                              void* d_out, int out_size, void* d_ws,
                              size_t ws_size, hipStream_t stream) {
  const float* x  = (const float*)d_in[0];
  const float* Wq = (const float*)d_in[1];
  const float* bq = (const float*)d_in[2];
  const float* Wk = (const float*)d_in[3];
  const float* bk = (const float*)d_in[4];
  const float* Wv = (const float*)d_in[5];
  const float* bv = (const float*)d_in[6];
  const float* Wo = (const float*)d_in[7];
  const float* bo = (const float*)d_in[8];
  float* out = (float*)d_out;

  char* ws = (char*)d_ws;
  const size_t MB = 1024 * 1024;
  u16* Xhi = (u16*)ws;                      // alias attnHi
  u16* Xlo = (u16*)(ws + 8 * MB);           // alias attnLo
  u16* Khi  = (u16*)(ws + 16 * MB);
  u16* Klo  = (u16*)(ws + 16 * MB + 256 * 1024);
  u16* Vthi = (u16*)(ws + 16 * MB + 512 * 1024);
  u16* Vtlo = (u16*)(ws + 16 * MB + 768 * 1024);
  u16* Wqthi = (u16*)(ws + 17 * MB);
  u16* Wqtlo = (u16*)(ws + 19 * MB);
  u16* Wothi = (u16*)(ws + 21 * MB);
  u16* Wotlo = (u16*)(ws + 23 * MB);
  u16* Qhi = (u16*)d_out;
  u16* Qlo = Qhi + (size_t)M_ROWS * DM;     // 8MB offset, exact fit in d_out

  hipLaunchKernelGGL(split_x, dim3(2048), dim3(256), 0, stream, x, Xhi, Xlo);
  hipLaunchKernelGGL(tsplit, dim3(32, 32), dim3(256), 0, stream, Wq, Wqthi,
                     Wqtlo);
  hipLaunchKernelGGL(tsplit, dim3(32, 32), dim3(256), 0, stream, Wo, Wothi,
                     Wotlo);
  hipLaunchKernelGGL(kv_proj, dim3(M_ROWS / 4), dim3(256), 0, stream, x, Wk,
                     bk, Wv, bv, Khi, Klo, Vthi, Vtlo);
  hipLaunchKernelGGL(HIP_KERNEL_NAME(gemm_mfma<1>), dim3(256), dim3(256), 0,
                     stream, Xhi, Xlo, Wqthi, Wqtlo, bq, (float*)nullptr, Qhi,
                     Qlo);
  hipLaunchKernelGGL(flash_mfma, dim3(16, NH, NBATCH), dim3(256), 0, stream,
                     Qhi, Qlo, Khi, Klo, Vthi, Vtlo, Xhi, Xlo);
  hipLaunchKernelGGL(HIP_KERNEL_NAME(gemm_mfma<0>), dim3(256), dim3(256), 0,
                     stream, Xhi, Xlo, Wothi, Wotlo, bo, out, (u16*)nullptr,
                     (u16*)nullptr);
}

// Round 7
// 348.864 us; speedup vs baseline: 6.1181x; 1.0043x over previous
//
#include <hip/hip_runtime.h>
#include <cstdint>
#include <cstddef>

typedef unsigned short u16;
typedef unsigned int u32;
typedef __attribute__((ext_vector_type(8))) short short8;
typedef __attribute__((ext_vector_type(4))) float f32x4;

#define S_LEN 2048
#define NBATCH 2
#define DM 1024
#define DK 32
#define NH 32
#define M_ROWS 4096
#define SCALE 0.17677669529663687f  // 1/sqrt(32)

// ---- fp32 -> bf16 hi/lo split (hi = truncation, lo = rne(x - hi)) ----------
__device__ __forceinline__ u16 bf16_rne(float f) {
  u32 u = __float_as_uint(f);
  u32 r = (u + 0x7FFFu + ((u >> 16) & 1u)) >> 16;
  return (u16)r;
}
__device__ __forceinline__ void split2(float x, u16& hi, u16& lo) {
  u32 u = __float_as_uint(x);
  hi = (u16)(u >> 16);
  float hif = __uint_as_float(u & 0xFFFF0000u);
  lo = bf16_rne(x - hif);
}
__device__ __forceinline__ u32 pack2(float lo, float hi) {
  return (u32)bf16_rne(lo) | ((u32)bf16_rne(hi) << 16);
}
// async global->LDS, 16B per lane; dest = uniform base + lane*16
__device__ __forceinline__ void gl16(const u16* gsrc, u16* ldst) {
  __builtin_amdgcn_global_load_lds((const u32*)gsrc, (u32*)ldst, 16, 0, 0);
}

// ---------------------------------------------------------------------------
// split_x: fp32 array -> bf16 hi + lo arrays. (validated R4)
// ---------------------------------------------------------------------------
__global__ __launch_bounds__(256)
void split_x(const float* __restrict__ X, u16* __restrict__ Hi,
             u16* __restrict__ Lo) {
  const size_t i0 = ((size_t)blockIdx.x * 256 + threadIdx.x) * 8;
  const float4 v0 = *(const float4*)(X + i0);
  const float4 v1 = *(const float4*)(X + i0 + 4);
  const float f[8] = {v0.x, v0.y, v0.z, v0.w, v1.x, v1.y, v1.z, v1.w};
  u16 h[8], l[8];
#pragma unroll
  for (int e = 0; e < 8; ++e) split2(f[e], h[e], l[e]);
  uint4 hv, lv;
  hv.x = h[0] | ((u32)h[1] << 16); hv.y = h[2] | ((u32)h[3] << 16);
  hv.z = h[4] | ((u32)h[5] << 16); hv.w = h[6] | ((u32)h[7] << 16);
  lv.x = l[0] | ((u32)l[1] << 16); lv.y = l[2] | ((u32)l[3] << 16);
  lv.z = l[4] | ((u32)l[5] << 16); lv.w = l[6] | ((u32)l[7] << 16);
  *(uint4*)(Hi + i0) = hv;
  *(uint4*)(Lo + i0) = lv;
}

// ---------------------------------------------------------------------------
// tsplit: W (1024x1024 fp32) -> W^T hi/lo bf16 (N x K). (validated R4)
// ---------------------------------------------------------------------------
__global__ __launch_bounds__(256)
void tsplit(const float* __restrict__ W, u16* __restrict__ Thi,
            u16* __restrict__ Tlo) {
  __shared__ float tile[32][33];
  const int k0 = blockIdx.x * 32, n0 = blockIdx.y * 32;
  const int tx = threadIdx.x & 31, ty = threadIdx.x >> 5;
#pragma unroll
  for (int i = 0; i < 4; ++i)
    tile[ty + 8 * i][tx] = W[(size_t)(k0 + ty + 8 * i) * DM + n0 + tx];
  __syncthreads();
#pragma unroll
  for (int i = 0; i < 4; ++i) {
    const float v = tile[tx][ty + 8 * i];
    u16 h, l;
    split2(v, h, l);
    const size_t d = (size_t)(n0 + ty + 8 * i) * DM + k0 + tx;
    Thi[d] = h;
    Tlo[d] = l;
  }
}

// ---------------------------------------------------------------------------
// gemm2: bf16x3 MFMA GEMM, C(4096x1024) = A @ B^T + bias.
// 128x64 tile -> 512 blocks (2/CU); global_load_lds staging into frag-major
// LDS; double-buffered; ONE barrier per K-step (m97 structure).
// ---------------------------------------------------------------------------
template <int QMODE>
__global__ __launch_bounds__(256, 2)
void gemm2(const u16* __restrict__ Ahi, const u16* __restrict__ Alo,
           const u16* __restrict__ Bhi, const u16* __restrict__ Blo,
           const float* __restrict__ bias, float* __restrict__ C,
           u16* __restrict__ Ohi, u16* __restrict__ Olo) {
  __shared__ u16 ldsA[2][2][8][64][8];  // 32KB
  __shared__ u16 ldsB[2][2][4][64][8];  // 16KB
  const int t = threadIdx.x;
  const int wvi = t >> 6, l = t & 63;
  const int bid = blockIdx.x;
  const int wg = ((bid & 7) << 6) | (bid >> 3);  // bijective (512 = 8*64)
  const int m0 = (wg >> 4) * 128;
  const int n0 = (wg & 15) * 64;
  const int wr = wvi >> 1, wc = wvi & 1;
  const int lrow = l & 15, lk = (l >> 4) * 8;

  const u16* sbase =
      (wvi == 0) ? Ahi : (wvi == 1) ? Alo : (wvi == 2) ? Bhi : Blo;
  const int srow0 = (wvi < 2) ? m0 : n0;

  f32x4 acc[4][2];
#pragma unroll
  for (int i = 0; i < 4; ++i)
#pragma unroll
    for (int j = 0; j < 2; ++j) acc[i][j] = (f32x4){0.f, 0.f, 0.f, 0.f};

  auto issue = [&](int buf, int kk) {
    if (wvi < 2) {
#pragma unroll
      for (int mt = 0; mt < 8; ++mt)
        gl16(sbase + (size_t)(srow0 + mt * 16 + lrow) * DM + kk + lk,
             &ldsA[buf][wvi][mt][0][0]);
    } else {
#pragma unroll
      for (int nt = 0; nt < 4; ++nt)
        gl16(sbase + (size_t)(srow0 + nt * 16 + lrow) * DM + kk + lk,
             &ldsB[buf][wvi - 2][nt][0][0]);
    }
  };

  issue(0, 0);
  for (int ks = 0; ks < 32; ++ks) {
    const int cb = ks & 1;
    __syncthreads();
    if (ks < 31) issue(cb ^ 1, (ks + 1) * 32);

    short8 ah[4], alo[4], bh[2], bl[2];
#pragma unroll
    for (int i = 0; i < 4; ++i) {
      ah[i] = *(const short8*)&ldsA[cb][0][wr * 4 + i][l][0];
      alo[i] = *(const short8*)&ldsA[cb][1][wr * 4 + i][l][0];
    }
#pragma unroll
    for (int j = 0; j < 2; ++j) {
      bh[j] = *(const short8*)&ldsB[cb][0][wc * 2 + j][l][0];
      bl[j] = *(const short8*)&ldsB[cb][1][wc * 2 + j][l][0];
    }
#pragma unroll
    for (int i = 0; i < 4; ++i)
#pragma unroll
      for (int j = 0; j < 2; ++j) {
        acc[i][j] = __builtin_amdgcn_mfma_f32_16x16x32_bf16(ah[i], bh[j],
                                                            acc[i][j], 0, 0, 0);
        acc[i][j] = __builtin_amdgcn_mfma_f32_16x16x32_bf16(ah[i], bl[j],
                                                            acc[i][j], 0, 0, 0);
        acc[i][j] = __builtin_amdgcn_mfma_f32_16x16x32_bf16(alo[i], bh[j],
                                                            acc[i][j], 0, 0, 0);
      }
  }

  const int lcol = l & 15;
  float bj[2];
#pragma unroll
  for (int j = 0; j < 2; ++j) bj[j] = bias[n0 + wc * 32 + j * 16 + lcol];
#pragma unroll
  for (int i = 0; i < 4; ++i) {
    const int row0 = m0 + wr * 64 + i * 16 + (l >> 4) * 4;
#pragma unroll
    for (int j = 0; j < 2; ++j) {
      const int coln = n0 + wc * 32 + j * 16 + lcol;
#pragma unroll
      for (int q = 0; q < 4; ++q) {
        const float val = acc[i][j][q] + bj[j];
        if constexpr (QMODE == 0) {
          C[(size_t)(row0 + q) * DM + coln] = val;
        } else {
          u16 hh, ll;
          split2(val * SCALE, hh, ll);
          Ohi[(size_t)(row0 + q) * DM + coln] = hh;
          Olo[(size_t)(row0 + q) * DM + coln] = ll;
        }
      }
    }
  }
}

// ---------------------------------------------------------------------------
// K/V projection -> bf16 hi/lo (validated R6).
// ---------------------------------------------------------------------------
__global__ __launch_bounds__(256)
void kv_proj(const float* __restrict__ X, const float* __restrict__ Wk,
             const float* __restrict__ bk, const float* __restrict__ Wv,
             const float* __restrict__ bv, u16* __restrict__ Khi,
             u16* __restrict__ Klo, u16* __restrict__ Vthi,
             u16* __restrict__ Vtlo) {
  const int col = threadIdx.x & 63;
  const int rr = threadIdx.x >> 6;
  const int row = blockIdx.x * 4 + rr;
  const float* __restrict__ xr = X + (size_t)row * DM;
  const bool isK = col < DK;
  const int cc = isK ? col : col - DK;
  const float* __restrict__ w = (isK ? Wk : Wv) + cc;
  float acc = isK ? bk[cc] : bv[cc];
#pragma unroll 8
  for (int k = 0; k < DM; ++k) acc = fmaf(xr[k], w[(size_t)k * DK], acc);
  u16 h, l;
  split2(acc, h, l);
  if (isK) {
    Khi[(size_t)row * DK + cc] = h;
    Klo[(size_t)row * DK + cc] = l;
  } else {
    const size_t d =
        (size_t)(row >> 11) * DK * S_LEN + (size_t)cc * S_LEN + (row & 2047);
    Vthi[d] = h;
    Vtlo[d] = l;
  }
}

// ---------------------------------------------------------------------------
// flash_mfma2: global_load_lds staging (no LDS-write conflicts), stg dbuf,
// one barrier/iter; plds wave-private (no barrier). Math = validated R6.
// ---------------------------------------------------------------------------
__global__ __launch_bounds__(256, 4)
void flash_mfma2(const u16* __restrict__ Qhi, const u16* __restrict__ Qlo,
                 const u16* __restrict__ Khi, const u16* __restrict__ Klo,
                 const u16* __restrict__ Vthi, const u16* __restrict__ Vtlo,
                 u16* __restrict__ Ohi, u16* __restrict__ Olo) {
  __shared__ u16 stg[2][4][2][64][8];  // 16KB
  __shared__ u16 plds[4][2][64][8];    // 8KB
  const int a = blockIdx.y, b = blockIdx.z;
  const int tid = threadIdx.x;
  const int wv = tid >> 6, l = tid & 63;
  const int lq = l & 15, lc = l >> 4;
  const int q0w = blockIdx.x * 128 + wv * 32;
  const size_t bS = (size_t)b * S_LEN;
  const size_t bDS = (size_t)b * DK * S_LEN;

  short8 qh[2], ql[2];
#pragma unroll
  for (int mt = 0; mt < 2; ++mt) {
    const size_t off =
        (size_t)(b * S_LEN + q0w + mt * 16 + lq) * DM + a * DK + lc * 8;
    qh[mt] = *(const short8*)(Qhi + off);
    ql[mt] = *(const short8*)(Qlo + off);
  }

  f32x4 oacc[2][2];
#pragma unroll
  for (int mt = 0; mt < 2; ++mt)
#pragma unroll
    for (int et = 0; et < 2; ++et) oacc[mt][et] = (f32x4){0.f, 0.f, 0.f, 0.f};
  float lsum[2] = {0.f, 0.f};

  const u16* kbase = (wv == 0) ? Khi : Klo;
  const u16* vbase = (wv == 2) ? Vthi : Vtlo;

  auto issue = [&](int buf, int t0) {
    if (wv < 2) {
#pragma unroll
      for (int tt = 0; tt < 2; ++tt)
        gl16(kbase + (bS + t0 + tt * 16 + lq) * DK + lc * 8,
             &stg[buf][wv][tt][0][0]);
    } else {
#pragma unroll
      for (int tt = 0; tt < 2; ++tt)
        gl16(vbase + bDS + (size_t)(tt * 16 + lq) * S_LEN + t0 + lc * 8,
             &stg[buf][wv][tt][0][0]);
    }
  };

  issue(0, 0);
  for (int it = 0; it < 64; ++it) {
    const int cb = it & 1;
    __syncthreads();
    if (it < 63) issue(cb ^ 1, (it + 1) * 32);

    short8 kh[2], klo[2], vh[2], vl[2];
#pragma unroll
    for (int tt = 0; tt < 2; ++tt) {
      kh[tt] = *(const short8*)&stg[cb][0][tt][l][0];
      klo[tt] = *(const short8*)&stg[cb][1][tt][l][0];
      vh[tt] = *(const short8*)&stg[cb][2][tt][l][0];
      vl[tt] = *(const short8*)&stg[cb][3][tt][l][0];
    }
#pragma unroll
    for (int mt = 0; mt < 2; ++mt) {
      f32x4 s0 = (f32x4){0.f, 0.f, 0.f, 0.f};
      f32x4 s1 = (f32x4){0.f, 0.f, 0.f, 0.f};
      s0 = __builtin_amdgcn_mfma_f32_16x16x32_bf16(kh[0], qh[mt], s0, 0, 0, 0);
      s0 = __builtin_amdgcn_mfma_f32_16x16x32_bf16(kh[0], ql[mt], s0, 0, 0, 0);
      s0 = __builtin_amdgcn_mfma_f32_16x16x32_bf16(klo[0], qh[mt], s0, 0, 0, 0);
      s1 = __builtin_amdgcn_mfma_f32_16x16x32_bf16(kh[1], qh[mt], s1, 0, 0, 0);
      s1 = __builtin_amdgcn_mfma_f32_16x16x32_bf16(kh[1], ql[mt], s1, 0, 0, 0);
      s1 = __builtin_amdgcn_mfma_f32_16x16x32_bf16(klo[1], qh[mt], s1, 0, 0, 0);
      const float e0 = __expf(s0[0]), e1 = __expf(s0[1]);
      const float e2 = __expf(s0[2]), e3 = __expf(s0[3]);
      const float e4 = __expf(s1[0]), e5 = __expf(s1[1]);
      const float e6 = __expf(s1[2]), e7 = __expf(s1[3]);
      lsum[mt] += ((e0 + e1) + (e2 + e3)) + ((e4 + e5) + (e6 + e7));
      const u32 pA = pack2(e0, e1), pB = pack2(e2, e3);
      const u32 pC = pack2(e4, e5), pD = pack2(e6, e7);
      const int fl1 = ((lc >> 1) << 4) | lq;
      const int fl2 = (((lc >> 1) + 2) << 4) | lq;
      *(uint2*)&plds[wv][mt][fl1][(lc & 1) * 4] = make_uint2(pA, pB);
      *(uint2*)&plds[wv][mt][fl2][(lc & 1) * 4] = make_uint2(pC, pD);
    }
#pragma unroll
    for (int mt = 0; mt < 2; ++mt) {
      const short8 pf = *(const short8*)&plds[wv][mt][l][0];
      oacc[mt][0] = __builtin_amdgcn_mfma_f32_16x16x32_bf16(pf, vh[0],
                                                            oacc[mt][0], 0, 0, 0);
      oacc[mt][0] = __builtin_amdgcn_mfma_f32_16x16x32_bf16(pf, vl[0],
                                                            oacc[mt][0], 0, 0, 0);
      oacc[mt][1] = __builtin_amdgcn_mfma_f32_16x16x32_bf16(pf, vh[1],
                                                            oacc[mt][1], 0, 0, 0);
      oacc[mt][1] = __builtin_amdgcn_mfma_f32_16x16x32_bf16(pf, vl[1],
                                                            oacc[mt][1], 0, 0, 0);
    }
  }

#pragma unroll
  for (int mt = 0; mt < 2; ++mt) {
    float s = lsum[mt];
    s += __shfl_xor(s, 16);
    s += __shfl_xor(s, 32);
    const float inv = 1.f / s;
    float invr[4];
#pragma unroll
    for (int rg = 0; rg < 4; ++rg)
      invr[rg] = __int_as_float(__builtin_amdgcn_ds_bpermute(
          (((lc << 2) | rg)) << 2, __float_as_int(inv)));
    const size_t rb = (size_t)(b * S_LEN + q0w + mt * 16 + lc * 4);
#pragma unroll
    for (int et = 0; et < 2; ++et) {
#pragma unroll
      for (int rg = 0; rg < 4; ++rg) {
        const float val = oacc[mt][et][rg] * invr[rg];
        u16 hh, ll;
        split2(val, hh, ll);
        const size_t idx = (rb + rg) * DM + a * DK + et * 16 + lq;
        Ohi[idx] = hh;
        Olo[idx] = ll;
      }
    }
  }
}

// ---------------------------------------------------------------------------
extern "C" void kernel_launch(void* const* d_in, const int* in_sizes, int n_in,
                              void* d_out, int out_size, void* d_ws,
                              size_t ws_size, hipStream_t stream) {
  const float* x  = (const float*)d_in[0];
  const float* Wq = (const float*)d_in[1];
  const float* bq = (const float*)d_in[2];
  const float* Wk = (const float*)d_in[3];
  const float* bk = (const float*)d_in[4];
  const float* Wv = (const float*)d_in[5];
  const float* bv = (const float*)d_in[6];
  const float* Wo = (const float*)d_in[7];
  const float* bo = (const float*)d_in[8];
  float* out = (float*)d_out;

  char* ws = (char*)d_ws;
  const size_t MB = 1024 * 1024;
  u16* Xhi = (u16*)ws;
  u16* Xlo = (u16*)(ws + 8 * MB);
  u16* Khi  = (u16*)(ws + 16 * MB);
  u16* Klo  = (u16*)(ws + 16 * MB + 256 * 1024);
  u16* Vthi = (u16*)(ws + 16 * MB + 512 * 1024);
  u16* Vtlo = (u16*)(ws + 16 * MB + 768 * 1024);
  u16* Wqthi = (u16*)(ws + 17 * MB);
  u16* Wqtlo = (u16*)(ws + 19 * MB);
  u16* Wothi = (u16*)(ws + 21 * MB);
  u16* Wotlo = (u16*)(ws + 23 * MB);
  u16* Qhi = (u16*)d_out;
  u16* Qlo = Qhi + (size_t)M_ROWS * DM;

  hipLaunchKernelGGL(split_x, dim3(2048), dim3(256), 0, stream, x, Xhi, Xlo);
  hipLaunchKernelGGL(tsplit, dim3(32, 32), dim3(256), 0, stream, Wq, Wqthi,
                     Wqtlo);
  hipLaunchKernelGGL(tsplit, dim3(32, 32), dim3(256), 0, stream, Wo, Wothi,
                     Wotlo);
  hipLaunchKernelGGL(kv_proj, dim3(M_ROWS / 4), dim3(256), 0, stream, x, Wk,
                     bk, Wv, bv, Khi, Klo, Vthi, Vtlo);
  hipLaunchKernelGGL(HIP_KERNEL_NAME(gemm2<1>), dim3(512), dim3(256), 0,
                     stream, Xhi, Xlo, Wqthi, Wqtlo, bq, (float*)nullptr, Qhi,
                     Qlo);
  hipLaunchKernelGGL(flash_mfma2, dim3(16, NH, NBATCH), dim3(256), 0, stream,
                     Qhi, Qlo, Khi, Klo, Vthi, Vtlo, Xhi, Xlo);
  hipLaunchKernelGGL(HIP_KERNEL_NAME(gemm2<0>), dim3(512), dim3(256), 0,
                     stream, Xhi, Xlo, Wothi, Wotlo, bo, out, (u16*)nullptr,
                     (u16*)nullptr);
}

// Round 8
// 342.638 us; speedup vs baseline: 6.2293x; 1.0182x over previous
//
#include <hip/hip_runtime.h>
#include <hip/hip_bf16.h>
#include <cstdint>
#include <cstddef>

typedef unsigned short u16;
typedef unsigned int u32;
typedef __attribute__((ext_vector_type(8))) short short8;
typedef __attribute__((ext_vector_type(4))) float f32x4;

#define S_LEN 2048
#define NBATCH 2
#define DM 1024
#define DK 32
#define NH 32
#define M_ROWS 4096
#define SCALE 0.17677669529663687f  // 1/sqrt(32)

// ---- fp32 -> bf16 hi/lo split (hi = truncation, lo = rne(x - hi)) ----------
__device__ __forceinline__ u16 bf16_rne(float f) {
  u32 u = __float_as_uint(f);
  u32 r = (u + 0x7FFFu + ((u >> 16) & 1u)) >> 16;
  return (u16)r;
}
__device__ __forceinline__ void split2(float x, u16& hi, u16& lo) {
  u32 u = __float_as_uint(x);
  hi = (u16)(u >> 16);
  float hif = __uint_as_float(u & 0xFFFF0000u);
  lo = bf16_rne(x - hif);
}
// pack two f32 -> two bf16 (rne) in one u32; compiler emits v_cvt_pk_bf16_f32
__device__ __forceinline__ u32 pack2(float a, float b) {
  __hip_bfloat162 v;
  v.x = __float2bfloat16(a);
  v.y = __float2bfloat16(b);
  return *(u32*)&v;
}
// async global->LDS, 16B per lane; dest = uniform base + lane*16
__device__ __forceinline__ void gl16(const u16* gsrc, u16* ldst) {
  __builtin_amdgcn_global_load_lds((const u32*)gsrc, (u32*)ldst, 16, 0, 0);
}

// ---------------------------------------------------------------------------
// split_x: fp32 array -> bf16 hi + lo arrays. (validated R4)
// ---------------------------------------------------------------------------
__global__ __launch_bounds__(256)
void split_x(const float* __restrict__ X, u16* __restrict__ Hi,
             u16* __restrict__ Lo) {
  const size_t i0 = ((size_t)blockIdx.x * 256 + threadIdx.x) * 8;
  const float4 v0 = *(const float4*)(X + i0);
  const float4 v1 = *(const float4*)(X + i0 + 4);
  const float f[8] = {v0.x, v0.y, v0.z, v0.w, v1.x, v1.y, v1.z, v1.w};
  u16 h[8], l[8];
#pragma unroll
  for (int e = 0; e < 8; ++e) split2(f[e], h[e], l[e]);
  uint4 hv, lv;
  hv.x = h[0] | ((u32)h[1] << 16); hv.y = h[2] | ((u32)h[3] << 16);
  hv.z = h[4] | ((u32)h[5] << 16); hv.w = h[6] | ((u32)h[7] << 16);
  lv.x = l[0] | ((u32)l[1] << 16); lv.y = l[2] | ((u32)l[3] << 16);
  lv.z = l[4] | ((u32)l[5] << 16); lv.w = l[6] | ((u32)l[7] << 16);
  *(uint4*)(Hi + i0) = hv;
  *(uint4*)(Lo + i0) = lv;
}

// ---------------------------------------------------------------------------
// tsplit: W (1024x1024 fp32) -> W^T hi/lo bf16 (N x K). (validated R4)
// ---------------------------------------------------------------------------
__global__ __launch_bounds__(256)
void tsplit(const float* __restrict__ W, u16* __restrict__ Thi,
            u16* __restrict__ Tlo) {
  __shared__ float tile[32][33];
  const int k0 = blockIdx.x * 32, n0 = blockIdx.y * 32;
  const int tx = threadIdx.x & 31, ty = threadIdx.x >> 5;
#pragma unroll
  for (int i = 0; i < 4; ++i)
    tile[ty + 8 * i][tx] = W[(size_t)(k0 + ty + 8 * i) * DM + n0 + tx];
  __syncthreads();
#pragma unroll
  for (int i = 0; i < 4; ++i) {
    const float v = tile[tx][ty + 8 * i];
    u16 h, l;
    split2(v, h, l);
    const size_t d = (size_t)(n0 + ty + 8 * i) * DM + k0 + tx;
    Thi[d] = h;
    Tlo[d] = l;
  }
}

// ---------------------------------------------------------------------------
// gemm3: bf16x3 MFMA GEMM, C(4096x1024) = A @ B^T + bias.
// vs R7 gemm2: 3-deep LDS pipeline with per-wave COUNTED s_waitcnt vmcnt(N)
// + raw s_barrier (T3/T4): steady-state never drains to 0, so next-tile
// loads stay in flight across the barrier. Wave w stages one array per
// K-step (w0=Ahi 8 gl_lds, w1=Alo 8, w2=Bhi 4, w3=Blo 4) -> per-wave vmcnt
// accounting is exact (wait N = one tile's own loads still outstanding).
// 128x64 tile, 512 blocks (2/CU), XCD-contiguous swizzle.
// ---------------------------------------------------------------------------
template <int QMODE>
__global__ __launch_bounds__(256, 2)
void gemm3(const u16* __restrict__ Ahi, const u16* __restrict__ Alo,
           const u16* __restrict__ Bhi, const u16* __restrict__ Blo,
           const float* __restrict__ bias, float* __restrict__ C,
           u16* __restrict__ Ohi, u16* __restrict__ Olo) {
  __shared__ u16 ldsA[3][2][8][64][8];  // 48KB: [buf][hi/lo][mt][lane][8]
  __shared__ u16 ldsB[3][2][4][64][8];  // 24KB
  const int t = threadIdx.x;
  const int wvi = t >> 6, l = t & 63;
  const int bid = blockIdx.x;
  const int wg = ((bid & 7) << 6) | (bid >> 3);  // bijective (512 = 8*64)
  const int m0 = (wg >> 4) * 128;
  const int n0 = (wg & 15) * 64;
  const int wr = wvi >> 1, wc = wvi & 1;
  const int lrow = l & 15, lk = (l >> 4) * 8;

  const u16* sbase =
      (wvi == 0) ? Ahi : (wvi == 1) ? Alo : (wvi == 2) ? Bhi : Blo;
  const int srow0 = (wvi < 2) ? m0 : n0;

  f32x4 acc[4][2];
#pragma unroll
  for (int i = 0; i < 4; ++i)
#pragma unroll
    for (int j = 0; j < 2; ++j) acc[i][j] = (f32x4){0.f, 0.f, 0.f, 0.f};

  auto issue = [&](int buf, int kk) {
    if (wvi < 2) {
#pragma unroll
      for (int mt = 0; mt < 8; ++mt)
        gl16(sbase + (size_t)(srow0 + mt * 16 + lrow) * DM + kk + lk,
             &ldsA[buf][wvi][mt][0][0]);
    } else {
#pragma unroll
      for (int nt = 0; nt < 4; ++nt)
        gl16(sbase + (size_t)(srow0 + nt * 16 + lrow) * DM + kk + lk,
             &ldsB[buf][wvi - 2][nt][0][0]);
    }
  };

  issue(0, 0);
  issue(1, 32);
  for (int ks = 0; ks < 32; ++ks) {
    // counted wait: drain own tile-ks loads, keep tile-(ks+1) in flight
    if (ks == 31) {
      asm volatile("s_waitcnt vmcnt(0)" ::: "memory");
    } else if (wvi < 2) {
      asm volatile("s_waitcnt vmcnt(8)" ::: "memory");
    } else {
      asm volatile("s_waitcnt vmcnt(4)" ::: "memory");
    }
    __builtin_amdgcn_s_barrier();      // all waves drained their tile-ks
    __builtin_amdgcn_sched_barrier(0); // no hoisting above the barrier
    if (ks < 30) issue((ks + 2) % 3, (ks + 2) * 32);
    const int cb = ks % 3;

    short8 ah[4], alo[4], bh[2], bl[2];
#pragma unroll
    for (int i = 0; i < 4; ++i) {
      ah[i] = *(const short8*)&ldsA[cb][0][wr * 4 + i][l][0];
      alo[i] = *(const short8*)&ldsA[cb][1][wr * 4 + i][l][0];
    }
#pragma unroll
    for (int j = 0; j < 2; ++j) {
      bh[j] = *(const short8*)&ldsB[cb][0][wc * 2 + j][l][0];
      bl[j] = *(const short8*)&ldsB[cb][1][wc * 2 + j][l][0];
    }
#pragma unroll
    for (int i = 0; i < 4; ++i)
#pragma unroll
      for (int j = 0; j < 2; ++j) {
        acc[i][j] = __builtin_amdgcn_mfma_f32_16x16x32_bf16(ah[i], bh[j],
                                                            acc[i][j], 0, 0, 0);
        acc[i][j] = __builtin_amdgcn_mfma_f32_16x16x32_bf16(ah[i], bl[j],
                                                            acc[i][j], 0, 0, 0);
        acc[i][j] = __builtin_amdgcn_mfma_f32_16x16x32_bf16(alo[i], bh[j],
                                                            acc[i][j], 0, 0, 0);
      }
  }

  const int lcol = l & 15;
  float bj[2];
#pragma unroll
  for (int j = 0; j < 2; ++j) bj[j] = bias[n0 + wc * 32 + j * 16 + lcol];
#pragma unroll
  for (int i = 0; i < 4; ++i) {
    const int row0 = m0 + wr * 64 + i * 16 + (l >> 4) * 4;
#pragma unroll
    for (int j = 0; j < 2; ++j) {
      const int coln = n0 + wc * 32 + j * 16 + lcol;
#pragma unroll
      for (int q = 0; q < 4; ++q) {
        const float val = acc[i][j][q] + bj[j];
        if constexpr (QMODE == 0) {
          C[(size_t)(row0 + q) * DM + coln] = val;
        } else {
          u16 hh, ll;
          split2(val * SCALE, hh, ll);
          Ohi[(size_t)(row0 + q) * DM + coln] = hh;
          Olo[(size_t)(row0 + q) * DM + coln] = ll;
        }
      }
    }
  }
}

// ---------------------------------------------------------------------------
// K/V projection -> bf16 hi/lo (validated R6).
// ---------------------------------------------------------------------------
__global__ __launch_bounds__(256)
void kv_proj(const float* __restrict__ X, const float* __restrict__ Wk,
             const float* __restrict__ bk, const float* __restrict__ Wv,
             const float* __restrict__ bv, u16* __restrict__ Khi,
             u16* __restrict__ Klo, u16* __restrict__ Vthi,
             u16* __restrict__ Vtlo) {
  const int col = threadIdx.x & 63;
  const int rr = threadIdx.x >> 6;
  const int row = blockIdx.x * 4 + rr;
  const float* __restrict__ xr = X + (size_t)row * DM;
  const bool isK = col < DK;
  const int cc = isK ? col : col - DK;
  const float* __restrict__ w = (isK ? Wk : Wv) + cc;
  float acc = isK ? bk[cc] : bv[cc];
#pragma unroll 8
  for (int k = 0; k < DM; ++k) acc = fmaf(xr[k], w[(size_t)k * DK], acc);
  u16 h, l;
  split2(acc, h, l);
  if (isK) {
    Khi[(size_t)row * DK + cc] = h;
    Klo[(size_t)row * DK + cc] = l;
  } else {
    const size_t d =
        (size_t)(row >> 11) * DK * S_LEN + (size_t)cc * S_LEN + (row & 2047);
    Vthi[d] = h;
    Vtlo[d] = l;
  }
}

// ---------------------------------------------------------------------------
// flash3: MFMA flash attention (math = validated R6/R7), now with the same
// counted-vmcnt 3-buffer pipeline (each wave stages 2 gl_lds/tile: w0/w1=K
// hi/lo, w2/w3=Vt hi/lo) and pk-packed P conversion (v_cvt_pk_bf16_f32 via
// __float2bfloat16 pairs, identical rne rounding). plds stays wave-private
// (no barrier). Grid (16, 32, 2), 256 threads, 4 blocks/CU.
// ---------------------------------------------------------------------------
__global__ __launch_bounds__(256, 4)
void flash3(const u16* __restrict__ Qhi, const u16* __restrict__ Qlo,
            const u16* __restrict__ Khi, const u16* __restrict__ Klo,
            const u16* __restrict__ Vthi, const u16* __restrict__ Vtlo,
            u16* __restrict__ Ohi, u16* __restrict__ Olo) {
  __shared__ u16 stg[3][4][2][64][8];  // 24KB: [buf][Kh,Kl,Vh,Vl][tile]
  __shared__ u16 plds[4][2][64][8];    // 8KB, wave-private
  const int a = blockIdx.y, b = blockIdx.z;
  const int tid = threadIdx.x;
  const int wv = tid >> 6, l = tid & 63;
  const int lq = l & 15, lc = l >> 4;
  const int q0w = blockIdx.x * 128 + wv * 32;
  const size_t bS = (size_t)b * S_LEN;
  const size_t bDS = (size_t)b * DK * S_LEN;

  short8 qh[2], ql[2];
#pragma unroll
  for (int mt = 0; mt < 2; ++mt) {
    const size_t off =
        (size_t)(b * S_LEN + q0w + mt * 16 + lq) * DM + a * DK + lc * 8;
    qh[mt] = *(const short8*)(Qhi + off);
    ql[mt] = *(const short8*)(Qlo + off);
  }

  f32x4 oacc[2][2];
#pragma unroll
  for (int mt = 0; mt < 2; ++mt)
#pragma unroll
    for (int et = 0; et < 2; ++et) oacc[mt][et] = (f32x4){0.f, 0.f, 0.f, 0.f};
  float lsum[2] = {0.f, 0.f};

  const u16* kbase = (wv == 0) ? Khi : Klo;
  const u16* vbase = (wv == 2) ? Vthi : Vtlo;

  auto issue = [&](int buf, int t0) {
    if (wv < 2) {
#pragma unroll
      for (int tt = 0; tt < 2; ++tt)
        gl16(kbase + (bS + t0 + tt * 16 + lq) * DK + lc * 8,
             &stg[buf][wv][tt][0][0]);
    } else {
#pragma unroll
      for (int tt = 0; tt < 2; ++tt)
        gl16(vbase + bDS + (size_t)(tt * 16 + lq) * S_LEN + t0 + lc * 8,
             &stg[buf][wv][tt][0][0]);
    }
  };

  issue(0, 0);
  issue(1, 32);
  for (int it = 0; it < 64; ++it) {
    if (it == 63) {
      asm volatile("s_waitcnt vmcnt(0)" ::: "memory");
    } else {
      asm volatile("s_waitcnt vmcnt(2)" ::: "memory");
    }
    __builtin_amdgcn_s_barrier();
    __builtin_amdgcn_sched_barrier(0);
    if (it < 62) issue((it + 2) % 3, (it + 2) * 32);
    const int cb = it % 3;

    short8 kh[2], klo[2], vh[2], vl[2];
#pragma unroll
    for (int tt = 0; tt < 2; ++tt) {
      kh[tt] = *(const short8*)&stg[cb][0][tt][l][0];
      klo[tt] = *(const short8*)&stg[cb][1][tt][l][0];
      vh[tt] = *(const short8*)&stg[cb][2][tt][l][0];
      vl[tt] = *(const short8*)&stg[cb][3][tt][l][0];
    }
#pragma unroll
    for (int mt = 0; mt < 2; ++mt) {
      f32x4 s0 = (f32x4){0.f, 0.f, 0.f, 0.f};
      f32x4 s1 = (f32x4){0.f, 0.f, 0.f, 0.f};
      s0 = __builtin_amdgcn_mfma_f32_16x16x32_bf16(kh[0], qh[mt], s0, 0, 0, 0);
      s0 = __builtin_amdgcn_mfma_f32_16x16x32_bf16(kh[0], ql[mt], s0, 0, 0, 0);
      s0 = __builtin_amdgcn_mfma_f32_16x16x32_bf16(klo[0], qh[mt], s0, 0, 0, 0);
      s1 = __builtin_amdgcn_mfma_f32_16x16x32_bf16(kh[1], qh[mt], s1, 0, 0, 0);
      s1 = __builtin_amdgcn_mfma_f32_16x16x32_bf16(kh[1], ql[mt], s1, 0, 0, 0);
      s1 = __builtin_amdgcn_mfma_f32_16x16x32_bf16(klo[1], qh[mt], s1, 0, 0, 0);
      const float e0 = __expf(s0[0]), e1 = __expf(s0[1]);
      const float e2 = __expf(s0[2]), e3 = __expf(s0[3]);
      const float e4 = __expf(s1[0]), e5 = __expf(s1[1]);
      const float e6 = __expf(s1[2]), e7 = __expf(s1[3]);
      lsum[mt] += ((e0 + e1) + (e2 + e3)) + ((e4 + e5) + (e6 + e7));
      const u32 pA = pack2(e0, e1), pB = pack2(e2, e3);
      const u32 pC = pack2(e4, e5), pD = pack2(e6, e7);
      const int fl1 = ((lc >> 1) << 4) | lq;
      const int fl2 = (((lc >> 1) + 2) << 4) | lq;
      *(uint2*)&plds[wv][mt][fl1][(lc & 1) * 4] = make_uint2(pA, pB);
      *(uint2*)&plds[wv][mt][fl2][(lc & 1) * 4] = make_uint2(pC, pD);
    }
#pragma unroll
    for (int mt = 0; mt < 2; ++mt) {
      const short8 pf = *(const short8*)&plds[wv][mt][l][0];
      oacc[mt][0] = __builtin_amdgcn_mfma_f32_16x16x32_bf16(pf, vh[0],
                                                            oacc[mt][0], 0, 0, 0);
      oacc[mt][0] = __builtin_amdgcn_mfma_f32_16x16x32_bf16(pf, vl[0],
                                                            oacc[mt][0], 0, 0, 0);
      oacc[mt][1] = __builtin_amdgcn_mfma_f32_16x16x32_bf16(pf, vh[1],
                                                            oacc[mt][1], 0, 0, 0);
      oacc[mt][1] = __builtin_amdgcn_mfma_f32_16x16x32_bf16(pf, vl[1],
                                                            oacc[mt][1], 0, 0, 0);
    }
  }

#pragma unroll
  for (int mt = 0; mt < 2; ++mt) {
    float s = lsum[mt];
    s += __shfl_xor(s, 16);
    s += __shfl_xor(s, 32);
    const float inv = 1.f / s;
    float invr[4];
#pragma unroll
    for (int rg = 0; rg < 4; ++rg)
      invr[rg] = __int_as_float(__builtin_amdgcn_ds_bpermute(
          (((lc << 2) | rg)) << 2, __float_as_int(inv)));
    const size_t rb = (size_t)(b * S_LEN + q0w + mt * 16 + lc * 4);
#pragma unroll
    for (int et = 0; et < 2; ++et) {
#pragma unroll
      for (int rg = 0; rg < 4; ++rg) {
        const float val = oacc[mt][et][rg] * invr[rg];
        u16 hh, ll;
        split2(val, hh, ll);
        const size_t idx = (rb + rg) * DM + a * DK + et * 16 + lq;
        Ohi[idx] = hh;
        Olo[idx] = ll;
      }
    }
  }
}

// ---------------------------------------------------------------------------
// Workspace (25 MB), unchanged from validated R6/R7:
//  [0,8M) Xhi/attnHi   [8M,16M) Xlo/attnLo
//  [16M,+256K) Khi (+256K) Klo (+256K) Vthi (+256K) Vtlo
//  [17M) Wqthi [19M) Wqtlo [21M) Wothi [23M) Wotlo
// d_out holds Qhi (8MB) + Qlo (8MB) until O-proj overwrites it.
// ---------------------------------------------------------------------------
extern "C" void kernel_launch(void* const* d_in, const int* in_sizes, int n_in,
                              void* d_out, int out_size, void* d_ws,
                              size_t ws_size, hipStream_t stream) {
  const float* x  = (const float*)d_in[0];
  const float* Wq = (const float*)d_in[1];
  const float* bq = (const float*)d_in[2];
  const float* Wk = (const float*)d_in[3];
  const float* bk = (const float*)d_in[4];
  const float* Wv = (const float*)d_in[5];
  const float* bv = (const float*)d_in[6];
  const float* Wo = (const float*)d_in[7];
  const float* bo = (const float*)d_in[8];
  float* out = (float*)d_out;

  char* ws = (char*)d_ws;
  const size_t MB = 1024 * 1024;
  u16* Xhi = (u16*)ws;
  u16* Xlo = (u16*)(ws + 8 * MB);
  u16* Khi  = (u16*)(ws + 16 * MB);
  u16* Klo  = (u16*)(ws + 16 * MB + 256 * 1024);
  u16* Vthi = (u16*)(ws + 16 * MB + 512 * 1024);
  u16* Vtlo = (u16*)(ws + 16 * MB + 768 * 1024);
  u16* Wqthi = (u16*)(ws + 17 * MB);
  u16* Wqtlo = (u16*)(ws + 19 * MB);
  u16* Wothi = (u16*)(ws + 21 * MB);
  u16* Wotlo = (u16*)(ws + 23 * MB);
  u16* Qhi = (u16*)d_out;
  u16* Qlo = Qhi + (size_t)M_ROWS * DM;

  hipLaunchKernelGGL(split_x, dim3(2048), dim3(256), 0, stream, x, Xhi, Xlo);
  hipLaunchKernelGGL(tsplit, dim3(32, 32), dim3(256), 0, stream, Wq, Wqthi,
                     Wqtlo);
  hipLaunchKernelGGL(tsplit, dim3(32, 32), dim3(256), 0, stream, Wo, Wothi,
                     Wotlo);
  hipLaunchKernelGGL(kv_proj, dim3(M_ROWS / 4), dim3(256), 0, stream, x, Wk,
                     bk, Wv, bv, Khi, Klo, Vthi, Vtlo);
  hipLaunchKernelGGL(HIP_KERNEL_NAME(gemm3<1>), dim3(512), dim3(256), 0,
                     stream, Xhi, Xlo, Wqthi, Wqtlo, bq, (float*)nullptr, Qhi,
                     Qlo);
  hipLaunchKernelGGL(flash3, dim3(16, NH, NBATCH), dim3(256), 0, stream,
                     Qhi, Qlo, Khi, Klo, Vthi, Vtlo, Xhi, Xlo);
  hipLaunchKernelGGL(HIP_KERNEL_NAME(gemm3<0>), dim3(512), dim3(256), 0,
                     stream, Xhi, Xlo, Wothi, Wotlo, bo, out, (u16*)nullptr,
                     (u16*)nullptr);
}